// Round 1
// baseline (837.905 us; speedup 1.0000x reference)
//
#include <hip/hip_runtime.h>
#include <hip/hip_bf16.h>

#define DIM 64

// One wave (64 lanes) per edge; lane index = feature dim d.
// dr[e]  = sum_d head*rel*tail            (wave shuffle reduction)
// h[v]  += sigmoid(dr[e]) * head*rel      (f32 HW atomic scatter into dst row)
__global__ __launch_bounds__(256) void distmult_edge_kernel(
    const float* __restrict__ node_emb,
    const float* __restrict__ edge_emb,
    const int*   __restrict__ src,
    const int*   __restrict__ dst,
    float*       __restrict__ h,       // [N, DIM] (pre-zeroed)
    float*       __restrict__ dr_out,  // [E]
    int n_edges)
{
    const int e = (int)((blockIdx.x * (unsigned)blockDim.x + threadIdx.x) >> 6);
    const int d = threadIdx.x & 63;
    if (e >= n_edges) return;

    const int s = src[e];
    const int t = dst[e];

    const float hd = node_emb[(size_t)s * DIM + d];
    const float rl = edge_emb[(size_t)e * DIM + d];
    const float tl = node_emb[(size_t)t * DIM + d];

    const float p = hd * rl;       // head * rel  (reused for the message)
    float v = p * tl;              // head * rel * tail

    // wave64 all-reduce sum
    #pragma unroll
    for (int off = 32; off > 0; off >>= 1)
        v += __shfl_xor(v, off, 64);

    if (d == 0) dr_out[e] = v;

    const float sig = 1.0f / (1.0f + __expf(-v));
    unsafeAtomicAdd(&h[(size_t)t * DIM + d], sig * p);
}

extern "C" void kernel_launch(void* const* d_in, const int* in_sizes, int n_in,
                              void* d_out, int out_size, void* d_ws, size_t ws_size,
                              hipStream_t stream) {
    const float* node_emb = (const float*)d_in[0];
    const float* edge_emb = (const float*)d_in[1];
    const int*   src      = (const int*)d_in[2];
    const int*   dst      = (const int*)d_in[3];

    const int n_nodes = in_sizes[0] / DIM;
    const int n_edges = in_sizes[2];

    float* h  = (float*)d_out;                       // [n_nodes, DIM]
    float* dr = h + (size_t)n_nodes * DIM;           // [n_edges]

    // d_out is re-poisoned to 0xAA before each timed launch; h is accumulated
    // via atomics so it must start at zero every call.
    hipMemsetAsync(h, 0, (size_t)n_nodes * DIM * sizeof(float), stream);

    // 256 threads = 4 waves = 4 edges per block
    const int grid = (n_edges + 3) / 4;
    distmult_edge_kernel<<<grid, 256, 0, stream>>>(
        node_emb, edge_emb, src, dst, h, dr, n_edges);
}

// Round 2
// 809.735 us; speedup vs baseline: 1.0348x; 1.0348x over previous
//
#include <hip/hip_runtime.h>
#include <hip/hip_bf16.h>

#define DIM 64
#define CAP 128          // per-node bucket capacity; Poisson(mean=32) max ~60
#define OVF_CAP 65536

__device__ __forceinline__ float wave_reduce_sum(float v) {
    #pragma unroll
    for (int off = 32; off > 0; off >>= 1)
        v += __shfl_xor(v, off, 64);
    return v;
}

// Phase A: bucket edge ids by destination node.
__global__ __launch_bounds__(256) void bucket_kernel(
    const int* __restrict__ dst,
    int* __restrict__ cnt, int* __restrict__ ovf_cnt,
    int* __restrict__ ovf_list, int* __restrict__ list,
    int n_edges)
{
    const int e = blockIdx.x * 256 + threadIdx.x;
    if (e >= n_edges) return;
    const int t = dst[e];
    const int pos = atomicAdd(&cnt[t], 1);
    if (pos < CAP) {
        list[(size_t)t * CAP + pos] = e;
    } else {
        const int op = atomicAdd(ovf_cnt, 1);
        if (op < OVF_CAP) ovf_list[op] = e;
    }
}

// Phase B: one wave per node; lane = feature dim. Computes dr for every
// incident edge AND accumulates h[v] in registers — zero f32 atomics.
__global__ __launch_bounds__(256) void node_kernel(
    const float* __restrict__ node_emb,
    const float* __restrict__ edge_emb,
    const int*   __restrict__ src,
    const int*   __restrict__ cnt,
    const int*   __restrict__ list,
    float* __restrict__ h,
    float* __restrict__ dr,
    int n_nodes)
{
    const int v = (blockIdx.x * 256 + threadIdx.x) >> 6;
    const int d = threadIdx.x & 63;
    if (v >= n_nodes) return;

    int deg = cnt[v]; if (deg > CAP) deg = CAP;
    const int* lst = list + (size_t)v * CAP;
    const float tl = node_emb[(size_t)v * DIM + d];

    float acc = 0.f;
    int i = 0;
    // unroll x2: two independent edge-row loads in flight per iteration
    for (; i + 2 <= deg; i += 2) {
        const int e0 = lst[i], e1 = lst[i + 1];
        const int s0 = src[e0], s1 = src[e1];
        const float hd0 = node_emb[(size_t)s0 * DIM + d];
        const float rl0 = edge_emb[(size_t)e0 * DIM + d];
        const float hd1 = node_emb[(size_t)s1 * DIM + d];
        const float rl1 = edge_emb[(size_t)e1 * DIM + d];
        const float p0 = hd0 * rl0, p1 = hd1 * rl1;
        const float v0 = wave_reduce_sum(p0 * tl);
        const float v1 = wave_reduce_sum(p1 * tl);
        if (d == 0) { dr[e0] = v0; dr[e1] = v1; }
        acc += p0 / (1.f + __expf(-v0));   // sigmoid(v0) * p0
        acc += p1 / (1.f + __expf(-v1));
    }
    if (i < deg) {
        const int e0 = lst[i];
        const int s0 = src[e0];
        const float hd0 = node_emb[(size_t)s0 * DIM + d];
        const float rl0 = edge_emb[(size_t)e0 * DIM + d];
        const float p0 = hd0 * rl0;
        const float v0 = wave_reduce_sum(p0 * tl);
        if (d == 0) dr[e0] = v0;
        acc += p0 / (1.f + __expf(-v0));
    }
    h[(size_t)v * DIM + d] = acc;   // plain store — h fully written here
}

// Phase C: overflow edges (expected count: 0) via the round-1 atomic path.
// Runs after node_kernel (stream order), so atomicAdd onto h is safe.
__global__ __launch_bounds__(256) void overflow_kernel(
    const float* __restrict__ node_emb,
    const float* __restrict__ edge_emb,
    const int*   __restrict__ src,
    const int*   __restrict__ dst,
    const int*   __restrict__ ovf_cnt,
    const int*   __restrict__ ovf_list,
    float* __restrict__ h,
    float* __restrict__ dr)
{
    int n = *ovf_cnt; if (n > OVF_CAP) n = OVF_CAP;
    const int wave = (blockIdx.x * 256 + threadIdx.x) >> 6;
    const int d = threadIdx.x & 63;
    const int nwaves = gridDim.x * 4;
    for (int i = wave; i < n; i += nwaves) {
        const int e = ovf_list[i];
        const int s = src[e], t = dst[e];
        const float hd = node_emb[(size_t)s * DIM + d];
        const float rl = edge_emb[(size_t)e * DIM + d];
        const float tl = node_emb[(size_t)t * DIM + d];
        const float p = hd * rl;
        const float v = wave_reduce_sum(p * tl);
        if (d == 0) dr[e] = v;
        unsafeAtomicAdd(&h[(size_t)t * DIM + d], p / (1.f + __expf(-v)));
    }
}

// Fallback (ws too small): round-1 single-pass atomic kernel.
__global__ __launch_bounds__(256) void edge_atomic_kernel(
    const float* __restrict__ node_emb,
    const float* __restrict__ edge_emb,
    const int*   __restrict__ src,
    const int*   __restrict__ dst,
    float* __restrict__ h,
    float* __restrict__ dr,
    int n_edges)
{
    const int e = (int)((blockIdx.x * (unsigned)blockDim.x + threadIdx.x) >> 6);
    const int d = threadIdx.x & 63;
    if (e >= n_edges) return;
    const int s = src[e], t = dst[e];
    const float hd = node_emb[(size_t)s * DIM + d];
    const float rl = edge_emb[(size_t)e * DIM + d];
    const float tl = node_emb[(size_t)t * DIM + d];
    const float p = hd * rl;
    const float v = wave_reduce_sum(p * tl);
    if (d == 0) dr[e] = v;
    unsafeAtomicAdd(&h[(size_t)t * DIM + d], p / (1.f + __expf(-v)));
}

extern "C" void kernel_launch(void* const* d_in, const int* in_sizes, int n_in,
                              void* d_out, int out_size, void* d_ws, size_t ws_size,
                              hipStream_t stream) {
    const float* node_emb = (const float*)d_in[0];
    const float* edge_emb = (const float*)d_in[1];
    const int*   src      = (const int*)d_in[2];
    const int*   dst      = (const int*)d_in[3];

    const int n_nodes = in_sizes[0] / DIM;
    const int n_edges = in_sizes[2];

    float* h  = (float*)d_out;                 // [n_nodes, DIM]
    float* dr = h + (size_t)n_nodes * DIM;     // [n_edges]

    // Workspace layout (ints): [cnt n_nodes][ovf_cnt 1][pad 63][ovf_list OVF_CAP][list n_nodes*CAP]
    const size_t need = ((size_t)n_nodes + 64 + OVF_CAP + (size_t)n_nodes * CAP) * sizeof(int);

    if (ws_size < need) {
        // Fallback: atomic scatter path (correct, slower).
        hipMemsetAsync(h, 0, (size_t)n_nodes * DIM * sizeof(float), stream);
        edge_atomic_kernel<<<(n_edges + 3) / 4, 256, 0, stream>>>(
            node_emb, edge_emb, src, dst, h, dr, n_edges);
        return;
    }

    int* cnt      = (int*)d_ws;
    int* ovf_cnt  = cnt + n_nodes;
    int* ovf_list = cnt + n_nodes + 64;
    int* list     = ovf_list + OVF_CAP;

    // zero cnt + ovf_cnt (ws is re-poisoned to 0xAA before every call)
    hipMemsetAsync(cnt, 0, (size_t)(n_nodes + 64) * sizeof(int), stream);

    bucket_kernel<<<(n_edges + 255) / 256, 256, 0, stream>>>(
        dst, cnt, ovf_cnt, ovf_list, list, n_edges);

    node_kernel<<<(n_nodes * 64 + 255) / 256, 256, 0, stream>>>(
        node_emb, edge_emb, src, cnt, list, h, dr, n_nodes);

    overflow_kernel<<<64, 256, 0, stream>>>(
        node_emb, edge_emb, src, dst, ovf_cnt, ovf_list, h, dr);
}

// Round 4
// 739.052 us; speedup vs baseline: 1.1338x; 1.0956x over previous
//
#include <hip/hip_runtime.h>
#include <hip/hip_bf16.h>

#define DIM 64
#define CAP 128          // per-node bucket capacity; Poisson(mean=32) max ~60. Multiple of 4.
#define OVF_CAP 65536

typedef float v4f __attribute__((ext_vector_type(4)));
typedef int   v4i __attribute__((ext_vector_type(4)));

__device__ __forceinline__ float wave_reduce_sum(float v) {
    #pragma unroll
    for (int off = 32; off > 0; off >>= 1)
        v += __shfl_xor(v, off, 64);
    return v;
}

// Phase A: bucket edge ids by destination node.
__global__ __launch_bounds__(256) void bucket_kernel(
    const int* __restrict__ dst,
    int* __restrict__ cnt, int* __restrict__ ovf_cnt,
    int* __restrict__ ovf_list, int* __restrict__ list,
    int n_edges)
{
    const int e = blockIdx.x * 256 + threadIdx.x;
    if (e >= n_edges) return;
    const int t = dst[e];
    const int pos = atomicAdd(&cnt[t], 1);
    if (pos < CAP) {
        list[(size_t)t * CAP + pos] = e;
    } else {
        const int op = atomicAdd(ovf_cnt, 1);
        if (op < OVF_CAP) ovf_list[op] = e;
    }
}

// Phase B: one wave per node. 4 edges per iteration: 16 lanes per edge,
// each lane holds a v4f (16 lanes x 4 = 64 dims). Zero f32 atomics.
__global__ __launch_bounds__(256) void node_kernel(
    const v4f* __restrict__ node_emb4,   // [N, 16] v4f
    const v4f* __restrict__ edge_emb4,   // [E, 16] v4f
    const int* __restrict__ src,
    const int* __restrict__ cnt,
    const int* __restrict__ list,
    v4f*   __restrict__ h4,              // [N, 16] v4f
    float* __restrict__ dr,              // [E]
    int n_nodes)
{
    const int v    = (blockIdx.x * 256 + threadIdx.x) >> 6;
    const int lane = threadIdx.x & 63;
    const int g    = lane >> 4;   // which of the 4 edges in this batch
    const int p    = lane & 15;   // v4f slot within the 64-dim row
    if (v >= n_nodes) return;

    int deg = cnt[v]; if (deg > CAP) deg = CAP;
    const int* lst = list + (size_t)v * CAP;

    const v4f tl = node_emb4[(size_t)v * 16 + p];   // tail row, loop-invariant

    v4f acc = (v4f){0.f, 0.f, 0.f, 0.f};

    for (int i = 0; i < deg; i += 4) {
        // wave-uniform 16B load of 4 edge ids (lst is 512B-aligned per node,
        // i is a multiple of 4; entries beyond deg clamped to lst[i] below)
        const v4i e4 = *(const v4i*)(lst + i);
        const bool active = (i + g) < deg;
        int e = e4.x;
        if (g == 1) e = e4.y;
        if (g == 2) e = e4.z;
        if (g == 3) e = e4.w;
        if (!active) e = e4.x;                 // lst[i] is always valid here
        const int s = src[e];

        const v4f hd = node_emb4[(size_t)s * 16 + p];
        const v4f rl = __builtin_nontemporal_load(&edge_emb4[(size_t)e * 16 + p]);

        v4f pr = hd * rl;

        float dv = pr.x * tl.x + pr.y * tl.y + pr.z * tl.z + pr.w * tl.w;
        // reduce across the 16 lanes of this edge-group
        dv += __shfl_xor(dv, 1, 64);
        dv += __shfl_xor(dv, 2, 64);
        dv += __shfl_xor(dv, 4, 64);
        dv += __shfl_xor(dv, 8, 64);

        if (active) {
            if (p == 0) __builtin_nontemporal_store(dv, &dr[e]);
            const float sig = 1.f / (1.f + __expf(-dv));
            acc += sig * pr;
        }
    }

    // combine the 4 edge-groups' partial accumulators (lanes with same p)
    acc.x += __shfl_xor(acc.x, 16, 64); acc.y += __shfl_xor(acc.y, 16, 64);
    acc.z += __shfl_xor(acc.z, 16, 64); acc.w += __shfl_xor(acc.w, 16, 64);
    acc.x += __shfl_xor(acc.x, 32, 64); acc.y += __shfl_xor(acc.y, 32, 64);
    acc.z += __shfl_xor(acc.z, 32, 64); acc.w += __shfl_xor(acc.w, 32, 64);

    if (g == 0) __builtin_nontemporal_store(acc, &h4[(size_t)v * 16 + p]);
}

// Phase C: overflow edges (expected count: 0) via the atomic path.
__global__ __launch_bounds__(256) void overflow_kernel(
    const float* __restrict__ node_emb,
    const float* __restrict__ edge_emb,
    const int*   __restrict__ src,
    const int*   __restrict__ dst,
    const int*   __restrict__ ovf_cnt,
    const int*   __restrict__ ovf_list,
    float* __restrict__ h,
    float* __restrict__ dr)
{
    int n = *ovf_cnt; if (n > OVF_CAP) n = OVF_CAP;
    const int wave = (blockIdx.x * 256 + threadIdx.x) >> 6;
    const int d = threadIdx.x & 63;
    const int nwaves = gridDim.x * 4;
    for (int i = wave; i < n; i += nwaves) {
        const int e = ovf_list[i];
        const int s = src[e], t = dst[e];
        const float hd = node_emb[(size_t)s * DIM + d];
        const float rl = edge_emb[(size_t)e * DIM + d];
        const float tl = node_emb[(size_t)t * DIM + d];
        const float p = hd * rl;
        const float v = wave_reduce_sum(p * tl);
        if (d == 0) dr[e] = v;
        unsafeAtomicAdd(&h[(size_t)t * DIM + d], p / (1.f + __expf(-v)));
    }
}

// Fallback (ws too small): single-pass atomic kernel.
__global__ __launch_bounds__(256) void edge_atomic_kernel(
    const float* __restrict__ node_emb,
    const float* __restrict__ edge_emb,
    const int*   __restrict__ src,
    const int*   __restrict__ dst,
    float* __restrict__ h,
    float* __restrict__ dr,
    int n_edges)
{
    const int e = (int)((blockIdx.x * (unsigned)blockDim.x + threadIdx.x) >> 6);
    const int d = threadIdx.x & 63;
    if (e >= n_edges) return;
    const int s = src[e], t = dst[e];
    const float hd = node_emb[(size_t)s * DIM + d];
    const float rl = edge_emb[(size_t)e * DIM + d];
    const float tl = node_emb[(size_t)t * DIM + d];
    const float p = hd * rl;
    const float v = wave_reduce_sum(p * tl);
    if (d == 0) dr[e] = v;
    unsafeAtomicAdd(&h[(size_t)t * DIM + d], p / (1.f + __expf(-v)));
}

extern "C" void kernel_launch(void* const* d_in, const int* in_sizes, int n_in,
                              void* d_out, int out_size, void* d_ws, size_t ws_size,
                              hipStream_t stream) {
    const float* node_emb = (const float*)d_in[0];
    const float* edge_emb = (const float*)d_in[1];
    const int*   src      = (const int*)d_in[2];
    const int*   dst      = (const int*)d_in[3];

    const int n_nodes = in_sizes[0] / DIM;
    const int n_edges = in_sizes[2];

    float* h  = (float*)d_out;                 // [n_nodes, DIM]
    float* dr = h + (size_t)n_nodes * DIM;     // [n_edges]

    // Workspace (ints): [cnt n_nodes][ovf_cnt 1][pad 63][ovf_list OVF_CAP][list n_nodes*CAP]
    const size_t need = ((size_t)n_nodes + 64 + OVF_CAP + (size_t)n_nodes * CAP) * sizeof(int);

    if (ws_size < need) {
        (void)hipMemsetAsync(h, 0, (size_t)n_nodes * DIM * sizeof(float), stream);
        edge_atomic_kernel<<<(n_edges + 3) / 4, 256, 0, stream>>>(
            node_emb, edge_emb, src, dst, h, dr, n_edges);
        return;
    }

    int* cnt      = (int*)d_ws;
    int* ovf_cnt  = cnt + n_nodes;
    int* ovf_list = cnt + n_nodes + 64;
    int* list     = ovf_list + OVF_CAP;        // 16B-aligned: (n_nodes+64+OVF_CAP)%4==0

    (void)hipMemsetAsync(cnt, 0, (size_t)(n_nodes + 64) * sizeof(int), stream);

    bucket_kernel<<<(n_edges + 255) / 256, 256, 0, stream>>>(
        dst, cnt, ovf_cnt, ovf_list, list, n_edges);

    node_kernel<<<(n_nodes * 64 + 255) / 256, 256, 0, stream>>>(
        (const v4f*)node_emb, (const v4f*)edge_emb, src, cnt, list,
        (v4f*)h, dr, n_nodes);

    overflow_kernel<<<64, 256, 0, stream>>>(
        node_emb, edge_emb, src, dst, ovf_cnt, ovf_list, h, dr);
}